// Round 3
// baseline (240.367 us; speedup 1.0000x reference)
//
#include <hip/hip_runtime.h>

#define DEV __device__ __forceinline__

constexpr int A_ = 64, DE = 128, M_ = 512, DH = 64;

DEV float wred_sum64(float v) {
#pragma unroll
    for (int o = 1; o < 64; o <<= 1) v += __shfl_xor(v, o, 64);
    return v;
}

// ---------------- Kernel 1: per-(b,m) hyperbolic dH2 + log_map ----------------
// one wave per (b,m) row; lane = dim (dh=64)
__global__ __launch_bounds__(256) void k_hyp(const float* __restrict__ curr_hyp,
                                             const float* __restrict__ demo_hyp,
                                             float* __restrict__ dH2,
                                             float* __restrict__ logv) {
    const int lane = threadIdx.x & 63;
    const int r    = (blockIdx.x << 2) + (threadIdx.x >> 6);  // [0, B*M)
    const int b    = r >> 9;                                  // M=512

    float x = curr_hyp[(b << 6) + lane];
    float y = demo_hyp[((size_t)r << 6) + lane];
    const float mx = 1.0f - 1e-5f;

    float x2r = wred_sum64(x * x);
    float xn  = fmaxf(sqrtf(x2r), 1e-15f);
    float sx  = xn > mx ? mx / xn : 1.0f;
    x *= sx;
    float x2 = x2r * sx * sx;
    float y2r = wred_sum64(y * y);
    float yn  = fmaxf(sqrtf(y2r), 1e-15f);
    float sy  = yn > mx ? mx / yn : 1.0f;
    y *= sy;
    float y2 = y2r * sy * sy;

    float xy = wred_sum64(x * y);
    float num = (1.f - 2.f * xy + y2) * (-x) + (1.f - x2) * y;
    float den = fmaxf(1.f - 2.f * xy + x2 * y2, 1e-15f);
    float u   = num / den;

    float u2  = wred_sum64(u * u);
    float un  = fmaxf(sqrtf(u2), 1e-15f);
    float arg = fminf(un, 1.f - 1e-7f);
    float at  = 0.5f * __logf((1.f + arg) / (1.f - arg));  // atanh

    if (lane == 0) dH2[r] = 4.f * at * at;

    float lamden = fmaxf(1.f - x2, 1e-15f);  // 2/lambda
    float ls     = lamden * at / un;
    logv[((size_t)r << 6) + lane] = ls * u;
}

// ---------------- Kernel 2: contiguous streaming + per-a flash partials ----------------
// grid = B*32 blocks (b = blk>>5, mc = blk&31); 1024 threads.
// Block streams demo_rho[b, mc*16 : mc*16+16, :, :]  == 512 KB FULLY CONTIGUOUS.
// Thread (a = t>>4, dp = t&15) owns attention column a, de dims [dp*8, dp*8+8).
// Per-a flash state is thread-private: no cross-lane softmax shuffles, no LDS, no barriers.
__global__ __launch_bounds__(1024) void k_stream(const float* __restrict__ curr_rho,
                                                 const float* __restrict__ demo_rho,
                                                 const float* __restrict__ dH2,
                                                 float* __restrict__ ws_m,
                                                 float* __restrict__ ws_s,
                                                 float* __restrict__ ws_e,
                                                 float* __restrict__ ws_sc) {
    const int t   = threadIdx.x;
    const int mi  = t >> 4;   // a
    const int dp  = t & 15;
    const int blk = blockIdx.x;
    const int b   = blk >> 5, mc = blk & 31;
    const int m0  = mc << 4;

    float qf[8];
    {
        const float* qp = curr_rho + ((size_t)(b * 64 + mi)) * DE + dp * 8;
        float4 q0 = *(const float4*)qp;
        float4 q1 = *(const float4*)(qp + 4);
        qf[0] = q0.x; qf[1] = q0.y; qf[2] = q0.z; qf[3] = q0.w;
        qf[4] = q1.x; qf[5] = q1.y; qf[6] = q1.z; qf[7] = q1.w;
    }

    float dh2r[16];
    {
        const float* dp2 = dH2 + (b << 9) + m0;
        *(float4*)&dh2r[0]  = *(const float4*)(dp2);
        *(float4*)&dh2r[4]  = *(const float4*)(dp2 + 4);
        *(float4*)&dh2r[8]  = *(const float4*)(dp2 + 8);
        *(float4*)&dh2r[12] = *(const float4*)(dp2 + 12);
    }

    // chunk row = A_*DE = 8192 floats = 32 KB
    const float* tp = demo_rho + ((size_t)(b * M_ + m0)) * (A_ * DE) + mi * DE + dp * 8;

    // depth-3 register prefetch pipeline
    float4 pa0 = *(const float4*)tp;
    float4 pa1 = *(const float4*)(tp + 4);
    float4 pb0 = *(const float4*)(tp + 8192);
    float4 pb1 = *(const float4*)(tp + 8192 + 4);
    float4 pc0 = *(const float4*)(tp + 16384);
    float4 pc1 = *(const float4*)(tp + 16384 + 4);

    float e_acc[8];
#pragma unroll
    for (int j = 0; j < 8; j++) e_acc[j] = 0.f;
    float gmax = -1e30f, gsum = 0.f;

    float* scp = ws_sc + ((size_t)blk * 16) * 64;  // [16 chunks][64 a], flat == [b][m][a]

#pragma unroll
    for (int c = 0; c < 16; ++c) {
        float4 n0 = make_float4(0.f, 0.f, 0.f, 0.f);
        float4 n1 = n0;
        if (c + 3 < 16) {
            const float* np = tp + (size_t)(c + 3) * 8192;
            n0 = *(const float4*)np;
            n1 = *(const float4*)(np + 4);
        }
        float kf[8];
        kf[0] = pa0.x; kf[1] = pa0.y; kf[2] = pa0.z; kf[3] = pa0.w;
        kf[4] = pa1.x; kf[5] = pa1.y; kf[6] = pa1.z; kf[7] = pa1.w;

        float ps = 0.f;
#pragma unroll
        for (int j = 0; j < 8; j++) { float d = qf[j] - kf[j]; ps += d * d; }
        ps += __shfl_xor(ps, 1, 64);
        ps += __shfl_xor(ps, 2, 64);
        ps += __shfl_xor(ps, 4, 64);
        ps += __shfl_xor(ps, 8, 64);  // uniform over the 16-lane dp group

        float sc = -(dh2r[c] + ps);
        if (dp == 0) scp[c * 64 + mi] = sc;  // raw score, for alpha@logv in combine

        // per-a online flash (one score per chunk per a; no cross-lane state)
        float gnew = fmaxf(gmax, sc);
        float r1   = __expf(gmax - gnew);   // c==0: exp(-inf)=0
        float w    = __expf(sc - gnew);
        gsum = fmaf(gsum, r1, w);
#pragma unroll
        for (int j = 0; j < 8; j++) e_acc[j] = fmaf(w, kf[j], e_acc[j] * r1);
        gmax = gnew;

        pa0 = pb0; pa1 = pb1; pb0 = pc0; pb1 = pc1; pc0 = n0; pc1 = n1;
    }

    // write unnormalized partials
    float* ep = ws_e + ((size_t)(blk * 64 + mi)) * 128 + dp * 8;
    *(float4*)ep       = make_float4(e_acc[0], e_acc[1], e_acc[2], e_acc[3]);
    *(float4*)(ep + 4) = make_float4(e_acc[4], e_acc[5], e_acc[6], e_acc[7]);
    if (dp == 0) {
        ws_m[blk * 64 + mi] = gmax;
        ws_s[blk * 64 + mi] = gsum;
    }
}

// ---------------- Kernel 3: flash combine + v + exp_map + matmul + LN ----------------
// one block per (b,a); 256 threads = 4 waves.
__global__ __launch_bounds__(256) void k_comb(const float* __restrict__ curr_hyp,
                                              const float* __restrict__ logv,
                                              const float* __restrict__ ws_m,
                                              const float* __restrict__ ws_s,
                                              const float* __restrict__ ws_e,
                                              const float* __restrict__ ws_sc,
                                              const float* __restrict__ We,
                                              const float* __restrict__ Wh,
                                              const float* __restrict__ gamma,
                                              const float* __restrict__ beta,
                                              float* __restrict__ out) {
    __shared__ float facL[32];
    __shared__ float sMS[2];
    __shared__ float ehL[192];     // [0:128) e_out, [128:192) h
    __shared__ float vpart[4][64];

    const int t   = threadIdx.x;
    const int blk = blockIdx.x;
    const int b   = blk >> 6, a = blk & 63;

    // ---- step 1: merge the 32 per-chunk flash states (wave 0, lanes 0..31) ----
    float g = -1e30f, s = 0.f;
    if (t < 32) {
        g = ws_m[(size_t)(b * 32 + t) * 64 + a];
        s = ws_s[(size_t)(b * 32 + t) * 64 + a];
    }
    float M = g;
    M = fmaxf(M, __shfl_xor(M, 1, 64));
    M = fmaxf(M, __shfl_xor(M, 2, 64));
    M = fmaxf(M, __shfl_xor(M, 4, 64));
    M = fmaxf(M, __shfl_xor(M, 8, 64));
    M = fmaxf(M, __shfl_xor(M, 16, 64));
    float fac = __expf(g - M);
    float Sp  = s * fac;
    Sp += __shfl_xor(Sp, 1, 64);
    Sp += __shfl_xor(Sp, 2, 64);
    Sp += __shfl_xor(Sp, 4, 64);
    Sp += __shfl_xor(Sp, 8, 64);
    Sp += __shfl_xor(Sp, 16, 64);
    if (t < 32) facL[t] = fac;
    if (t == 0) { sMS[0] = M; sMS[1] = Sp; }
    __syncthreads();
    const float Mg   = sMS[0];
    const float invS = 1.f / sMS[1];

    // ---- step 2: e_out[d] = sum_mc e_part[mc][d]*fac[mc] / S  (threads 0..127) ----
    if (t < 128) {
        float acc = 0.f;
#pragma unroll
        for (int mc = 0; mc < 32; ++mc)
            acc = fmaf(ws_e[((size_t)((b * 32 + mc) * 64 + a)) * 128 + t], facL[mc], acc);
        ehL[t] = acc * invS;
    }

    // ---- step 3: v[dh] = sum_m exp(sc[m]-M)*logv[m][dh] (all 4 waves, 128 m each) ----
    {
        const int dh = t & 63, sg = t >> 6;
        const float* lvb = logv  + ((size_t)(b * M_ + sg * 128)) * 64 + dh;
        const float* scb = ws_sc + ((size_t)(b * M_ + sg * 128)) * 64 + a;
        float vac = 0.f;
#pragma unroll 8
        for (int i = 0; i < 128; ++i) {
            float w = __expf(scb[(size_t)i * 64] - Mg);
            vac = fmaf(w, lvb[(size_t)i * 64], vac);
        }
        vpart[sg][dh] = vac;
    }
    __syncthreads();

    // ---- step 4: exp_map + We/Wh matmul + LN (wave 0) ----
    if (t < 64) {
        const int lane = t;
        float v = (vpart[0][lane] + vpart[1][lane] + vpart[2][lane] + vpart[3][lane]) * invS;

        const float mx = 1.0f - 1e-5f;
        float x = curr_hyp[(b << 6) + lane];
        float x2r = wred_sum64(x * x);
        float xn  = fmaxf(sqrtf(x2r), 1e-15f);
        float sx  = xn > mx ? mx / xn : 1.f;
        x *= sx;
        float x2 = x2r * sx * sx;
        float lamden = fmaxf(1.f - x2, 1e-15f);  // 2/lambda

        float v2 = wred_sum64(v * v);
        float vn = fmaxf(sqrtf(v2), 1e-15f);
        float targ   = vn / lamden;              // lambda*vnorm/2
        float e2     = __expf(2.f * targ);
        float factor = 1.f - 2.f / (e2 + 1.f);   // tanh, inf-safe
        float wvv    = v * (factor / vn);

        float w2 = wred_sum64(wvv * wvv);
        float xw = wred_sum64(x * wvv);
        float num = (1.f + 2.f * xw + w2) * x + (1.f - x2) * wvv;
        float den = fmaxf(1.f + 2.f * xw + x2 * w2, 1e-15f);
        float h   = num / den;
        float h2  = wred_sum64(h * h);
        float hn  = fmaxf(sqrtf(h2), 1e-15f);
        float shh = hn > mx ? mx / hn : 1.f;
        h *= shh;
        ehL[128 + lane] = h;  // same-wave visibility

        float ze = 0.f;
        const float* werow = We + lane * 128;
#pragma unroll
        for (int d0 = 0; d0 < 128; d0 += 4) {
            float4 wv4 = *(const float4*)(werow + d0);
            ze = fmaf(ehL[d0 + 0], wv4.x, ze);
            ze = fmaf(ehL[d0 + 1], wv4.y, ze);
            ze = fmaf(ehL[d0 + 2], wv4.z, ze);
            ze = fmaf(ehL[d0 + 3], wv4.w, ze);
        }
        float zh = 0.f;
        const float* whrow = Wh + lane * 64;
#pragma unroll
        for (int d0 = 0; d0 < 64; d0 += 4) {
            float4 wv4 = *(const float4*)(whrow + d0);
            zh = fmaf(ehL[128 + d0 + 0], wv4.x, zh);
            zh = fmaf(ehL[128 + d0 + 1], wv4.y, zh);
            zh = fmaf(ehL[128 + d0 + 2], wv4.z, zh);
            zh = fmaf(ehL[128 + d0 + 3], wv4.w, zh);
        }
        float ssum = wred_sum64(ze + zh);
        float mean = ssum * (1.f / 128.f);
        float sq   = wred_sum64(ze * ze + zh * zh);
        float var  = sq * (1.f / 128.f) - mean * mean;
        float rinv = rsqrtf(var + 1e-5f);
        float oe = (ze - mean) * rinv * gamma[lane] + beta[lane];
        float oh = (zh - mean) * rinv * gamma[64 + lane] + beta[64 + lane];
        out[(size_t)blk * 128 + lane]      = oe;
        out[(size_t)blk * 128 + 64 + lane] = oh;
    }
}

// ---------------- Fallback: round-1 monolithic kernel (1.06 MB workspace, known-passing) ----------------
__global__ __launch_bounds__(512, 4) void k_main_fb(const float* __restrict__ curr_rho,
                                                    const float* __restrict__ demo_rho,
                                                    const float* __restrict__ curr_hyp,
                                                    const float* __restrict__ dH2,
                                                    const float* __restrict__ logv,
                                                    const float* __restrict__ We,
                                                    const float* __restrict__ Wh,
                                                    const float* __restrict__ gamma,
                                                    const float* __restrict__ beta,
                                                    float* __restrict__ out) {
    __shared__ __align__(16) float rede[32 * 132];
    __shared__ float lds_sc[512];
    __shared__ float lds_dh[512];
    __shared__ float redm[8];
    __shared__ float reds[8];
    __shared__ float vpart[8][64];
    __shared__ float eh[192];

    const int t    = threadIdx.x;
    const int lane = t & 63;
    const int wv   = t >> 6;
    const int dp   = t & 15;
    const int mi   = t >> 4;
    const int blk  = blockIdx.x;
    const int b    = blk >> 6, a = blk & 63;

    lds_dh[t] = dH2[(b << 9) + t];

    float qf[8];
    {
        float4 q0 = *(const float4*)(curr_rho + (size_t)blk * DE + dp * 8);
        float4 q1 = *(const float4*)(curr_rho + (size_t)blk * DE + dp * 8 + 4);
        qf[0] = q0.x; qf[1] = q0.y; qf[2] = q0.z; qf[3] = q0.w;
        qf[4] = q1.x; qf[5] = q1.y; qf[6] = q1.z; qf[7] = q1.w;
    }

    const size_t rowStride = (size_t)A_ * DE;
    const size_t cstep     = (size_t)32 * rowStride;
    const float* tp = demo_rho + ((size_t)b * M_ * A_ + a) * DE + (size_t)mi * rowStride + dp * 8;

    __syncthreads();

    float4 ka0 = *(const float4*)tp;
    float4 ka1 = *(const float4*)(tp + 4);
    float4 kb0 = *(const float4*)(tp + cstep);
    float4 kb1 = *(const float4*)(tp + cstep + 4);

    float e_acc[8];
#pragma unroll
    for (int j = 0; j < 8; j++) e_acc[j] = 0.f;
    float gmax = -1e30f, gsum = 0.f;

#pragma unroll 2
    for (int c = 0; c < 16; ++c) {
        float4 n0, n1;
        if (c + 2 < 16) {
            const float* np = tp + (size_t)(c + 2) * cstep;
            n0 = *(const float4*)np;
            n1 = *(const float4*)(np + 4);
        }
        float kf[8];
        kf[0] = ka0.x; kf[1] = ka0.y; kf[2] = ka0.z; kf[3] = ka0.w;
        kf[4] = ka1.x; kf[5] = ka1.y; kf[6] = ka1.z; kf[7] = ka1.w;

        float ps = 0.f;
#pragma unroll
        for (int j = 0; j < 8; j++) { float d = qf[j] - kf[j]; ps += d * d; }
        ps += __shfl_xor(ps, 1, 64);
        ps += __shfl_xor(ps, 2, 64);
        ps += __shfl_xor(ps, 4, 64);
        ps += __shfl_xor(ps, 8, 64);
        float sc = -(lds_dh[c * 32 + mi] + ps);
        if (dp == 0) lds_sc[c * 32 + mi] = sc;

        float lm = fmaxf(sc, __shfl_xor(sc, 16, 64));
        lm = fmaxf(lm, __shfl_xor(lm, 32, 64));
        float gnew = fmaxf(gmax, lm);
        float r1   = __expf(gmax - gnew);
        float wexp = __expf(sc - gnew);
        float wsum = wexp + __shfl_xor(wexp, 16, 64);
        wsum += __shfl_xor(wsum, 32, 64);
        gsum = fmaf(gsum, r1, wsum);
#pragma unroll
        for (int j = 0; j < 8; j++) e_acc[j] = fmaf(wexp, kf[j], e_acc[j] * r1);
        gmax = gnew;

        ka0 = kb0; ka1 = kb1; kb0 = n0; kb1 = n1;
    }

    if (lane == 0) { redm[wv] = gmax; reds[wv] = gsum; }
    __syncthreads();

    float M = redm[0];
#pragma unroll
    for (int w = 1; w < 8; w++) M = fmaxf(M, redm[w]);
    float S = 0.f;
#pragma unroll
    for (int w = 0; w < 8; w++) S += reds[w] * __expf(redm[w] - M);
    const float inv = 1.f / S;
    const float fw  = __expf(gmax - M);

    float al = __expf(lds_sc[t] - M) * inv;

    *(float4*)&rede[mi * 132 + dp * 8] =
        make_float4(e_acc[0] * fw, e_acc[1] * fw, e_acc[2] * fw, e_acc[3] * fw);
    *(float4*)&rede[mi * 132 + dp * 8 + 4] =
        make_float4(e_acc[4] * fw, e_acc[5] * fw, e_acc[6] * fw, e_acc[7] * fw);
    lds_sc[t] = al;
    __syncthreads();

    if (t < 128) {
        float s = 0.f;
#pragma unroll
        for (int g = 0; g < 32; g++) s += rede[g * 132 + t];
        eh[t] = s * inv;
    }

    {
        const float* lvb = logv + ((size_t)(b * M_) + wv * 64) * DH;
        float acc = 0.f;
#pragma unroll 8
        for (int i = 0; i < 64; ++i)
            acc = fmaf(lds_sc[wv * 64 + i], lvb[(size_t)i * DH + lane], acc);
        vpart[wv][lane] = acc;
    }
    __syncthreads();

    if (wv == 0) {
        float v = 0.f;
#pragma unroll
        for (int w = 0; w < 8; w++) v += vpart[w][lane];

        const float mx = 1.0f - 1e-5f;
        float x = curr_hyp[(b << 6) + lane];
        float x2r = wred_sum64(x * x);
        float xn  = fmaxf(sqrtf(x2r), 1e-15f);
        float sx  = xn > mx ? mx / xn : 1.f;
        x *= sx;
        float x2 = x2r * sx * sx;
        float lamden = fmaxf(1.f - x2, 1e-15f);

        float v2 = wred_sum64(v * v);
        float vn = fmaxf(sqrtf(v2), 1e-15f);
        float targ   = vn / lamden;
        float e2     = __expf(2.f * targ);
        float factor = 1.f - 2.f / (e2 + 1.f);
        float wvv    = v * (factor / vn);

        float w2 = wred_sum64(wvv * wvv);
        float xw = wred_sum64(x * wvv);
        float num = (1.f + 2.f * xw + w2) * x + (1.f - x2) * wvv;
        float den = fmaxf(1.f + 2.f * xw + x2 * w2, 1e-15f);
        float h   = num / den;
        float h2  = wred_sum64(h * h);
        float hn  = fmaxf(sqrtf(h2), 1e-15f);
        float shh = hn > mx ? mx / hn : 1.f;
        h *= shh;
        eh[128 + lane] = h;

        float ze = 0.f;
        const float* werow = We + lane * 128;
#pragma unroll
        for (int d0 = 0; d0 < 128; d0 += 4) {
            float4 wv4 = *(const float4*)(werow + d0);
            ze = fmaf(eh[d0 + 0], wv4.x, ze);
            ze = fmaf(eh[d0 + 1], wv4.y, ze);
            ze = fmaf(eh[d0 + 2], wv4.z, ze);
            ze = fmaf(eh[d0 + 3], wv4.w, ze);
        }
        float zh = 0.f;
        const float* whrow = Wh + lane * 64;
#pragma unroll
        for (int d0 = 0; d0 < 64; d0 += 4) {
            float4 wv4 = *(const float4*)(whrow + d0);
            zh = fmaf(eh[128 + d0 + 0], wv4.x, zh);
            zh = fmaf(eh[128 + d0 + 1], wv4.y, zh);
            zh = fmaf(eh[128 + d0 + 2], wv4.z, zh);
            zh = fmaf(eh[128 + d0 + 3], wv4.w, zh);
        }
        float ssum = wred_sum64(ze + zh);
        float mean = ssum * (1.f / 128.f);
        float sq   = wred_sum64(ze * ze + zh * zh);
        float var  = sq * (1.f / 128.f) - mean * mean;
        float rinv = rsqrtf(var + 1e-5f);
        float oe = (ze - mean) * rinv * gamma[lane] + beta[lane];
        float oh = (zh - mean) * rinv * gamma[64 + lane] + beta[64 + lane];
        out[(size_t)blk * 128 + lane]      = oe;
        out[(size_t)blk * 128 + 64 + lane] = oh;
    }
}

extern "C" void kernel_launch(void* const* d_in, const int* in_sizes, int n_in,
                              void* d_out, int out_size, void* d_ws, size_t ws_size,
                              hipStream_t stream) {
    const float* curr_rho = (const float*)d_in[0];
    const float* curr_hyp = (const float*)d_in[1];
    const float* demo_rho = (const float*)d_in[2];
    const float* demo_hyp = (const float*)d_in[3];
    const float* We       = (const float*)d_in[4];
    const float* Wh       = (const float*)d_in[5];
    const float* gamma    = (const float*)d_in[6];
    const float* beta     = (const float*)d_in[7];
    float* out = (float*)d_out;

    float* ws   = (float*)d_ws;
    float* dH2  = ws;            // 4096 floats
    float* logv = ws + 4096;     // 262144 floats

    k_hyp<<<1024, 256, 0, stream>>>(curr_hyp, demo_hyp, dH2, logv);

    // split-M path needs 2,658,304 floats = 10,633,216 B of workspace
    const size_t NEED = (size_t)2658304 * sizeof(float);
    if (ws_size >= NEED) {
        float* ws_m  = ws + 266240;    // 8*32*64
        float* ws_s  = ws + 282624;    // 8*32*64
        float* ws_e  = ws + 299008;    // 8*32*64*128
        float* ws_sc = ws + 2396160;   // 8*512*64
        k_stream<<<256, 1024, 0, stream>>>(curr_rho, demo_rho, dH2, ws_m, ws_s, ws_e, ws_sc);
        k_comb<<<512, 256, 0, stream>>>(curr_hyp, logv, ws_m, ws_s, ws_e, ws_sc,
                                        We, Wh, gamma, beta, out);
    } else {
        k_main_fb<<<512, 512, 0, stream>>>(curr_rho, demo_rho, curr_hyp, dH2, logv,
                                           We, Wh, gamma, beta, out);
    }
}

// Round 4
// 221.602 us; speedup vs baseline: 1.0847x; 1.0847x over previous
//
#include <hip/hip_runtime.h>

#define DEV __device__ __forceinline__

constexpr int A_ = 64, DE = 128, M_ = 512, DH = 64;

DEV float wred_sum64(float v) {
#pragma unroll
    for (int o = 1; o < 64; o <<= 1) v += __shfl_xor(v, o, 64);
    return v;
}

// ---------------- Kernel 1: per-(b,m) hyperbolic dH2 + log_map ----------------
__global__ __launch_bounds__(256) void k_hyp(const float* __restrict__ curr_hyp,
                                             const float* __restrict__ demo_hyp,
                                             float* __restrict__ dH2,
                                             float* __restrict__ logv) {
    const int lane = threadIdx.x & 63;
    const int r    = (blockIdx.x << 2) + (threadIdx.x >> 6);  // [0, B*M)
    const int b    = r >> 9;                                  // M=512

    float x = curr_hyp[(b << 6) + lane];
    float y = demo_hyp[((size_t)r << 6) + lane];
    const float mx = 1.0f - 1e-5f;

    float x2r = wred_sum64(x * x);
    float xn  = fmaxf(sqrtf(x2r), 1e-15f);
    float sx  = xn > mx ? mx / xn : 1.0f;
    x *= sx;
    float x2 = x2r * sx * sx;
    float y2r = wred_sum64(y * y);
    float yn  = fmaxf(sqrtf(y2r), 1e-15f);
    float sy  = yn > mx ? mx / yn : 1.0f;
    y *= sy;
    float y2 = y2r * sy * sy;

    float xy = wred_sum64(x * y);
    float num = (1.f - 2.f * xy + y2) * (-x) + (1.f - x2) * y;
    float den = fmaxf(1.f - 2.f * xy + x2 * y2, 1e-15f);
    float u   = num / den;

    float u2  = wred_sum64(u * u);
    float un  = fmaxf(sqrtf(u2), 1e-15f);
    float arg = fminf(un, 1.f - 1e-7f);
    float at  = 0.5f * __logf((1.f + arg) / (1.f - arg));  // atanh

    if (lane == 0) dH2[r] = 4.f * at * at;

    float lamden = fmaxf(1.f - x2, 1e-15f);  // 2/lambda
    float ls     = lamden * at / un;
    logv[((size_t)r << 6) + lane] = ls * u;
}

// ---------------- Kernel 2: a-quad streaming, 2KB contiguous wave reads ----------------
// grid = 8b x 4mq x 16aq = 512 blocks, 512 threads = 8 waves.
// Block streams demo_rho[b, mq*128:(mq+1)*128, aq*4:aq*4+4, :] : 2KB contiguous per
// wave-load-pair, 16KB contiguous per 8-row chunk (vs round-1's 512B scattered).
// Wave mi handles chunk row mi; lane: al = l>>4 (a within quad), dp = l&15 (d-octet).
// Per-thread flash state over its 16 m's; 8-way intra-block LDS combine; 4-way (mq)
// flash partials to workspace (1 MB total).
__global__ __launch_bounds__(512, 4) void k_stream2(const float* __restrict__ curr_rho,
                                                    const float* __restrict__ demo_rho,
                                                    const float* __restrict__ dH2,
                                                    float* __restrict__ ws_m,
                                                    float* __restrict__ ws_s,
                                                    float* __restrict__ ws_e,
                                                    float* __restrict__ ws_sc) {
    __shared__ float lds_dh[128];
    __shared__ float redm[8][4];
    __shared__ float reds[8][4];
    __shared__ __align__(16) float rede[8][512];

    const int t  = threadIdx.x;
    const int l  = t & 63;
    const int mi = t >> 6;          // wave = row-in-chunk, 0..7
    const int al = l >> 4;          // 0..3
    const int dp = l & 15;          // 0..15
    const int blk = blockIdx.x;
    const int b  = blk >> 6;
    const int rr = blk & 63;
    const int mq = rr >> 4;         // 0..3  (m-quarter)
    const int aq = rr & 15;         // 0..15 (a-quad)
    const int a  = aq * 4 + al;
    const int m0 = mq << 7;         // mq*128

    if (t < 128) lds_dh[t] = dH2[(b << 9) + m0 + t];

    float qf[8];
    {
        const float* qp = curr_rho + ((size_t)(b * 64 + a)) * DE + dp * 8;
        float4 q0 = *(const float4*)qp;
        float4 q1 = *(const float4*)(qp + 4);
        qf[0] = q0.x; qf[1] = q0.y; qf[2] = q0.z; qf[3] = q0.w;
        qf[4] = q1.x; qf[5] = q1.y; qf[6] = q1.z; qf[7] = q1.w;
    }

    // row = 64a*128d = 8192 floats (32KB); chunk = 8 rows = 65536 floats (256KB)
    const float* tp = demo_rho + ((size_t)(b * M_ + m0)) * (A_ * DE)
                    + (size_t)mi * 8192 + aq * 4 * DE + al * DE + dp * 8;
    const size_t CS = 65536;

    __syncthreads();  // lds_dh

    // depth-3 register prefetch
    float4 pa0 = *(const float4*)tp;
    float4 pa1 = *(const float4*)(tp + 4);
    float4 pb0 = *(const float4*)(tp + CS);
    float4 pb1 = *(const float4*)(tp + CS + 4);
    float4 pc0 = *(const float4*)(tp + 2 * CS);
    float4 pc1 = *(const float4*)(tp + 2 * CS + 4);

    float e_acc[8];
#pragma unroll
    for (int j = 0; j < 8; j++) e_acc[j] = 0.f;
    float gmax = -1e30f, gsum = 0.f;

#pragma unroll 4
    for (int c = 0; c < 16; ++c) {
        float4 n0 = make_float4(0.f, 0.f, 0.f, 0.f);
        float4 n1 = n0;
        if (c + 3 < 16) {
            const float* np = tp + (size_t)(c + 3) * CS;
            n0 = *(const float4*)np;
            n1 = *(const float4*)(np + 4);
        }
        float kf[8];
        kf[0] = pa0.x; kf[1] = pa0.y; kf[2] = pa0.z; kf[3] = pa0.w;
        kf[4] = pa1.x; kf[5] = pa1.y; kf[6] = pa1.z; kf[7] = pa1.w;

        float ps = 0.f;
#pragma unroll
        for (int j = 0; j < 8; j++) { float d = qf[j] - kf[j]; ps += d * d; }
        ps += __shfl_xor(ps, 1, 64);
        ps += __shfl_xor(ps, 2, 64);
        ps += __shfl_xor(ps, 4, 64);
        ps += __shfl_xor(ps, 8, 64);  // uniform over the 16-lane dp group (al fixed)

        float sc = -(lds_dh[c * 8 + mi] + ps);
        if (dp == 0)
            ws_sc[((size_t)(b * M_ + m0 + c * 8 + mi)) * 64 + a] = sc;

        // per-thread online flash (state uniform within dp-group)
        float gnew = fmaxf(gmax, sc);
        float r1   = __expf(gmax - gnew);   // c==0: exp(-inf)=0
        float w    = __expf(sc - gnew);
        gsum = fmaf(gsum, r1, w);
#pragma unroll
        for (int j = 0; j < 8; j++) e_acc[j] = fmaf(w, kf[j], e_acc[j] * r1);
        gmax = gnew;

        pa0 = pb0; pa1 = pb1; pb0 = pc0; pb1 = pc1; pc0 = n0; pc1 = n1;
    }

    // ---- intra-block combine over the 8 waves (mi), per a-column al ----
    if (dp == 0) { redm[mi][al] = gmax; reds[mi][al] = gsum; }
    __syncthreads();

    float Mb = redm[0][al];
#pragma unroll
    for (int k = 1; k < 8; k++) Mb = fmaxf(Mb, redm[k][al]);
    float Sb = 0.f;
#pragma unroll
    for (int k = 0; k < 8; k++) Sb += reds[k][al] * __expf(redm[k][al] - Mb);
    float fac = __expf(gmax - Mb);

    *(float4*)&rede[mi][al * 128 + dp * 8] =
        make_float4(e_acc[0] * fac, e_acc[1] * fac, e_acc[2] * fac, e_acc[3] * fac);
    *(float4*)&rede[mi][al * 128 + dp * 8 + 4] =
        make_float4(e_acc[4] * fac, e_acc[5] * fac, e_acc[6] * fac, e_acc[7] * fac);
    if (mi == 0 && dp == 0) {
        const int q = b * 4 + mq;
        ws_m[q * 64 + a] = Mb;
        ws_s[q * 64 + a] = Sb;
    }
    __syncthreads();

    // reduce over mi: thread -> (al2 = t>>7, dd = t&127)
    {
        const int al2 = t >> 7, dd = t & 127;
        float s = 0.f;
#pragma unroll
        for (int k = 0; k < 8; k++) s += rede[k][al2 * 128 + dd];
        ws_e[((size_t)(b * 4 + mq) * 64 + (aq * 4 + al2)) * 128 + dd] = s;
    }
}

// ---------------- Kernel 3: 4-way flash merge + v + exp_map + matmul + LN ----------------
// one block per (b,a); 256 threads = 4 waves.
__global__ __launch_bounds__(256) void k_comb2(const float* __restrict__ curr_hyp,
                                               const float* __restrict__ logv,
                                               const float* __restrict__ ws_m,
                                               const float* __restrict__ ws_s,
                                               const float* __restrict__ ws_e,
                                               const float* __restrict__ ws_sc,
                                               const float* __restrict__ We,
                                               const float* __restrict__ Wh,
                                               const float* __restrict__ gamma,
                                               const float* __restrict__ beta,
                                               float* __restrict__ out) {
    __shared__ float ehL[192];     // [0:128) e_out, [128:192) h
    __shared__ float vpart[4][64];

    const int t   = threadIdx.x;
    const int blk = blockIdx.x;
    const int b   = blk >> 6, a = blk & 63;

    // ---- step 1: merge the 4 mq flash states (every thread, uniform scalar loads) ----
    float m_[4], s_[4];
#pragma unroll
    for (int q = 0; q < 4; q++) {
        m_[q] = ws_m[(b * 4 + q) * 64 + a];
        s_[q] = ws_s[(b * 4 + q) * 64 + a];
    }
    float M = fmaxf(fmaxf(m_[0], m_[1]), fmaxf(m_[2], m_[3]));
    float S = 0.f;
#pragma unroll
    for (int q = 0; q < 4; q++) S += s_[q] * __expf(m_[q] - M);
    const float invS = 1.f / S;

    // ---- step 2: e_out[d] = sum_q e_q[d]*exp(m_q-M) / S  (threads 0..127) ----
    if (t < 128) {
        float acc = 0.f;
#pragma unroll
        for (int q = 0; q < 4; q++)
            acc = fmaf(ws_e[((size_t)(b * 4 + q) * 64 + a) * 128 + t], __expf(m_[q] - M), acc);
        ehL[t] = acc * invS;
    }

    // ---- step 3: v[dh] = sum_m exp(sc[m]-M)*logv[m][dh] (4 waves, 128 m each) ----
    {
        const int dh = t & 63, sg = t >> 6;
        const float* lvb = logv  + ((size_t)(b * M_ + sg * 128)) * 64 + dh;
        const float* scb = ws_sc + ((size_t)(b * M_ + sg * 128)) * 64 + a;
        float vac = 0.f;
#pragma unroll 8
        for (int i = 0; i < 128; ++i) {
            float w = __expf(scb[(size_t)i * 64] - M);
            vac = fmaf(w, lvb[(size_t)i * 64], vac);
        }
        vpart[sg][dh] = vac;
    }
    __syncthreads();

    // ---- step 4: exp_map + We/Wh matmul + LN (wave 0) ----
    if (t < 64) {
        const int lane = t;
        float v = (vpart[0][lane] + vpart[1][lane] + vpart[2][lane] + vpart[3][lane]) * invS;

        const float mx = 1.0f - 1e-5f;
        float x = curr_hyp[(b << 6) + lane];
        float x2r = wred_sum64(x * x);
        float xn  = fmaxf(sqrtf(x2r), 1e-15f);
        float sx  = xn > mx ? mx / xn : 1.f;
        x *= sx;
        float x2 = x2r * sx * sx;
        float lamden = fmaxf(1.f - x2, 1e-15f);  // 2/lambda

        float v2 = wred_sum64(v * v);
        float vn = fmaxf(sqrtf(v2), 1e-15f);
        float targ   = vn / lamden;              // lambda*vnorm/2
        float e2     = __expf(2.f * targ);
        float factor = 1.f - 2.f / (e2 + 1.f);   // tanh, inf-safe
        float wvv    = v * (factor / vn);

        float w2 = wred_sum64(wvv * wvv);
        float xw = wred_sum64(x * wvv);
        float num = (1.f + 2.f * xw + w2) * x + (1.f - x2) * wvv;
        float den = fmaxf(1.f + 2.f * xw + x2 * w2, 1e-15f);
        float h   = num / den;
        float h2  = wred_sum64(h * h);
        float hn  = fmaxf(sqrtf(h2), 1e-15f);
        float shh = hn > mx ? mx / hn : 1.f;
        h *= shh;
        ehL[128 + lane] = h;  // same-wave visibility

        float ze = 0.f;
        const float* werow = We + lane * 128;
#pragma unroll
        for (int d0 = 0; d0 < 128; d0 += 4) {
            float4 wv4 = *(const float4*)(werow + d0);
            ze = fmaf(ehL[d0 + 0], wv4.x, ze);
            ze = fmaf(ehL[d0 + 1], wv4.y, ze);
            ze = fmaf(ehL[d0 + 2], wv4.z, ze);
            ze = fmaf(ehL[d0 + 3], wv4.w, ze);
        }
        float zh = 0.f;
        const float* whrow = Wh + lane * 64;
#pragma unroll
        for (int d0 = 0; d0 < 64; d0 += 4) {
            float4 wv4 = *(const float4*)(whrow + d0);
            zh = fmaf(ehL[128 + d0 + 0], wv4.x, zh);
            zh = fmaf(ehL[128 + d0 + 1], wv4.y, zh);
            zh = fmaf(ehL[128 + d0 + 2], wv4.z, zh);
            zh = fmaf(ehL[128 + d0 + 3], wv4.w, zh);
        }
        float ssum = wred_sum64(ze + zh);
        float mean = ssum * (1.f / 128.f);
        float sq   = wred_sum64(ze * ze + zh * zh);
        float var  = sq * (1.f / 128.f) - mean * mean;
        float rinv = rsqrtf(var + 1e-5f);
        float oe = (ze - mean) * rinv * gamma[lane] + beta[lane];
        float oh = (zh - mean) * rinv * gamma[64 + lane] + beta[64 + lane];
        out[(size_t)blk * 128 + lane]      = oe;
        out[(size_t)blk * 128 + 64 + lane] = oh;
    }
}

extern "C" void kernel_launch(void* const* d_in, const int* in_sizes, int n_in,
                              void* d_out, int out_size, void* d_ws, size_t ws_size,
                              hipStream_t stream) {
    const float* curr_rho = (const float*)d_in[0];
    const float* curr_hyp = (const float*)d_in[1];
    const float* demo_rho = (const float*)d_in[2];
    const float* demo_hyp = (const float*)d_in[3];
    const float* We       = (const float*)d_in[4];
    const float* Wh       = (const float*)d_in[5];
    const float* gamma    = (const float*)d_in[6];
    const float* beta     = (const float*)d_in[7];
    float* out = (float*)d_out;

    // workspace layout (floats): total 794,624 = 3.1 MB (round-3 proved >=10.6 MB avail)
    float* ws    = (float*)d_ws;
    float* dH2   = ws;             // 4096
    float* logv  = ws + 4096;      // 262144
    float* ws_m  = ws + 266240;    // 2048   (8*4*64)
    float* ws_s  = ws + 268288;    // 2048
    float* ws_e  = ws + 270336;    // 262144 (8*4*64*128)
    float* ws_sc = ws + 532480;    // 262144 (8*512*64)

    k_hyp<<<1024, 256, 0, stream>>>(curr_hyp, demo_hyp, dH2, logv);
    k_stream2<<<512, 512, 0, stream>>>(curr_rho, demo_rho, dH2, ws_m, ws_s, ws_e, ws_sc);
    k_comb2<<<512, 256, 0, stream>>>(curr_hyp, logv, ws_m, ws_s, ws_e, ws_sc,
                                     We, Wh, gamma, beta, out);
}